// Round 1
// baseline (182.940 us; speedup 1.0000x reference)
//
#include <hip/hip_runtime.h>
#include <math.h>

// Problem geometry (fixed by the reference):
//   img:    [16, 3, 512, 512] fp32, NCHW
//   weight: [16777216, 3] fp32
//   bias:   [16777216, 3] fp32
//   out:    [16, 3, 512, 512] fp32
//
// out[b,c,h,w] = tanh(weight[idx[b,h,w], c] * img[b,c,h,w] + bias[idx[b,h,w], c])
// idx = (int32)( q0*65536.0f + q1*256.0f + q2 ), q_c = (img[b,c,h,w] + 1.0f) * 127.5f
//
// Index math uses __fadd_rn/__fmul_rn so hipcc can never fma-contract it —
// rounding must bit-match the numpy fp32 reference or we gather the wrong row.

#define HW_   (512 * 512)          // 262144 elements per channel plane
#define CHW_  (3 * HW_)            // elements per image
#define QUADS_PER_IMG (HW_ / 4)    // 65536 float4-quads per plane
#define N_QUADS (16 * QUADS_PER_IMG) // 1,048,576 total quads

__global__ __launch_bounds__(256) void
lut_affine_tanh_kernel(const float* __restrict__ img,
                       const float* __restrict__ weight,
                       const float* __restrict__ bias,
                       float* __restrict__ out) {
    int quad = blockIdx.x * blockDim.x + threadIdx.x;
    if (quad >= N_QUADS) return;

    int b = quad >> 16;                 // quad / QUADS_PER_IMG
    int p = (quad & (QUADS_PER_IMG - 1)) << 2;  // pixel offset within the plane

    const float* base = img + (size_t)b * CHW_ + p;
    // 3 coalesced 16B loads: 4 consecutive pixels on each channel plane
    float4 r = *(const float4*)(base);
    float4 g = *(const float4*)(base + HW_);
    float4 bb = *(const float4*)(base + 2 * HW_);

    const float* rp = &r.x;
    const float* gp = &g.x;
    const float* bp = &bb.x;

    float4 o0, o1, o2;
    float* o0p = &o0.x;
    float* o1p = &o1.x;
    float* o2p = &o2.x;

#pragma unroll
    for (int i = 0; i < 4; ++i) {
        float x0 = rp[i], x1 = gp[i], x2 = bp[i];
        // q = (x + 1) * 127.5, exact fp32 ops (no contraction)
        float q0 = __fmul_rn(__fadd_rn(x0, 1.0f), 127.5f);
        float q1 = __fmul_rn(__fadd_rn(x1, 1.0f), 127.5f);
        float q2 = __fmul_rn(__fadd_rn(x2, 1.0f), 127.5f);
        // s = (q0*65536 + q1*256) + q2, left-to-right, each op rounded
        float s = __fadd_rn(__fadd_rn(__fmul_rn(q0, 65536.0f),
                                      __fmul_rn(q1, 256.0f)),
                            q2);
        int idx = (int)s;  // truncation toward zero; s >= 0 here

        // Gather 3-vector weight & bias rows (12B each, random access)
        const float* wrow = weight + (size_t)idx * 3;
        const float* brow = bias   + (size_t)idx * 3;
        float w0 = wrow[0], w1 = wrow[1], w2 = wrow[2];
        float c0 = brow[0], c1 = brow[1], c2 = brow[2];

        o0p[i] = tanhf(fmaf(w0, x0, c0));
        o1p[i] = tanhf(fmaf(w1, x1, c1));
        o2p[i] = tanhf(fmaf(w2, x2, c2));
    }

    float* obase = out + (size_t)b * CHW_ + p;
    *(float4*)(obase)           = o0;
    *(float4*)(obase + HW_)     = o1;
    *(float4*)(obase + 2 * HW_) = o2;
}

extern "C" void kernel_launch(void* const* d_in, const int* in_sizes, int n_in,
                              void* d_out, int out_size, void* d_ws, size_t ws_size,
                              hipStream_t stream) {
    const float* img    = (const float*)d_in[0];
    const float* weight = (const float*)d_in[1];
    const float* bias   = (const float*)d_in[2];
    float* out = (float*)d_out;

    const int threads = 256;
    const int blocks  = N_QUADS / threads;  // 4096
    lut_affine_tanh_kernel<<<blocks, threads, 0, stream>>>(img, weight, bias, out);
}